// Round 16
// baseline (586.138 us; speedup 1.0000x reference)
//
#include <hip/hip_runtime.h>

#define N_NODES 100000
#define N_PAD   100096   // multiple of 64 for GEMM block tiles
#define N_EDGES 320000
#define NB      128
#define DIN     128
#define H       256
#define OUT_DIM 10
#define EPSV    1e-6f
#define SCAN_B  256
#define PSLICES 32
#define NBLK    (N_PAD / 64)   // 1564 GEMM row-tiles (BM=64)
#define NXCD    8

typedef unsigned short bf16_t;
typedef __attribute__((ext_vector_type(8))) short bf16x8;
typedef __attribute__((ext_vector_type(4))) float f32x4;

__device__ __forceinline__ float bf2f(bf16_t u) {
    union { unsigned int i; float f; } x;
    x.i = ((unsigned int)u) << 16;
    return x.f;
}
__device__ __forceinline__ bf16_t f2bf(float f) {
    union { float f; unsigned int i; } x;
    x.f = f;
    unsigned int r = x.i + 0x7fffu + ((x.i >> 16) & 1u);   // round-to-nearest-even
    return (bf16_t)(r >> 16);
}

// Bijective XCD-chunked blockIdx swizzle (m204 variant; works for nwg%8 != 0).
__device__ __forceinline__ int xcd_swz(int bid, int nwg) {
    int q = nwg / NXCD, r = nwg % NXCD;
    int x = bid % NXCD, j = bid / NXCD;
    int base = (x < r) ? x * (q + 1) : r * (q + 1) + (x - r) * q;
    return base + j;
}

// ---------------- degree (deg_out = deg[0:N], deg_in = deg[N:2N]) ----------------
__global__ void k_edge_deg(const int* __restrict__ src, const int* __restrict__ dst,
                           int* deg) {
    int e = blockIdx.x * blockDim.x + threadIdx.x;
    if (e < N_EDGES) {
        atomicAdd(&deg[src[e]], 1);
        atomicAdd(&deg[N_NODES + dst[e]], 1);
    }
}

// ---------------- fused: graph offsets (block 0) + packed rel table (all blocks) ----------------
__global__ void k_gstart_relpk(const int* __restrict__ bid, int* __restrict__ gstart,
                               float* __restrict__ countsf, unsigned int* __restrict__ relpk) {
    if (blockIdx.x == 0) {
        int b = threadIdx.x;
        if (b <= NB) {
            int lo = 0, hi = N_NODES;
            while (lo < hi) {
                int mid = (lo + hi) >> 1;
                if (bid[mid] < b) lo = mid + 1; else hi = mid;
            }
            gstart[b] = lo;
        }
        __syncthreads();
        if (b < NB) countsf[b] = (float)max(gstart[b + 1] - gstart[b], 1);
    }
    int idx = blockIdx.x * blockDim.x + threadIdx.x;   // over NBLK*16
    if (idx >= NBLK * 16) return;
    int t = idx >> 4, w = idx & 15;
    int row0 = t * 64;
    int g0 = bid[(row0 < N_NODES) ? row0 : (N_NODES - 1)];
    unsigned int pk = 0;
    for (int j = 0; j < 4; ++j) {
        int r = row0 + w * 4 + j;
        unsigned int rel = 255u;
        if (r < N_NODES) {
            int d = bid[r] - g0;
            rel = (d >= 0 && d < 255) ? (unsigned int)d : 255u;
        }
        pk |= rel << (8 * j);
    }
    relpk[idx] = pk;
}

// ---------------- hierarchical scan for CSR row_start ----------------
__global__ void k_scan1(const int* __restrict__ deg_in, int* incl, int* bsums) {
    __shared__ int s[SCAN_B];
    int i = blockIdx.x * SCAN_B + threadIdx.x;
    int v = (i < N_NODES) ? deg_in[i] : 0;
    s[threadIdx.x] = v;
    __syncthreads();
    for (int d = 1; d < SCAN_B; d <<= 1) {
        int t = (threadIdx.x >= d) ? s[threadIdx.x - d] : 0;
        __syncthreads();
        s[threadIdx.x] += t;
        __syncthreads();
    }
    if (i < N_NODES) incl[i] = s[threadIdx.x];
    if (threadIdx.x == SCAN_B - 1) bsums[blockIdx.x] = s[threadIdx.x];
}

__global__ void k_scan2(const int* __restrict__ bsums, int* boffs, int nb) {
    __shared__ int s[512];
    int t = threadIdx.x;
    int v = (t < nb) ? bsums[t] : 0;
    s[t] = v;
    __syncthreads();
    for (int d = 1; d < 512; d <<= 1) {
        int x = (t >= d) ? s[t - d] : 0;
        __syncthreads();
        s[t] += x;
        __syncthreads();
    }
    if (t < nb) boffs[t] = s[t] - v;   // exclusive
}

// scan3 + dinv fused (same grid, independent outputs)
__global__ void k_scan3(const int* __restrict__ deg, const int* __restrict__ incl,
                        const int* __restrict__ boffs, int* row_start, int* cursor,
                        float* dinv_src, float* dinv_dst) {
    int i = blockIdx.x * blockDim.x + threadIdx.x;
    if (i < N_NODES) {
        int ex = incl[i] - deg[N_NODES + i] + boffs[i / SCAN_B];
        row_start[i] = ex;
        cursor[i]    = ex;
        dinv_src[i] = rsqrtf((float)max(deg[i], 1));
        dinv_dst[i] = rsqrtf((float)max(deg[N_NODES + i], 1));
    }
    if (i == 0) row_start[N_NODES] = N_EDGES;
}

__global__ void k_scatter(const int* __restrict__ src, const int* __restrict__ dst,
                          int* cursor, int* csr_src) {
    int e = blockIdx.x * blockDim.x + threadIdx.x;
    if (e < N_EDGES) {
        int slot = atomicAdd(&cursor[dst[e]], 1);
        csr_src[slot] = src[e];
    }
}

// ---------------- weight convert + transpose (both tensors, one kernel) ----------------
__global__ void k_wt(const float* __restrict__ Wf, const float* __restrict__ Wr,
                     bf16_t* __restrict__ Wt0, bf16_t* __restrict__ Wt123) {
    int idx = blockIdx.x * 256 + threadIdx.x;
    if (idx < H * DIN) {                        // Wt0[c][k] = bf16(Wf[k][c])
        int c = idx / DIN, k = idx % DIN;
        Wt0[idx] = f2bf(Wf[k * H + c]);
        return;
    }
    idx -= H * DIN;
    if (idx >= 3 * H * H) return;               // Wt123[l][c][k] = bf16(Wr[l][k][c])
    int l = idx / (H * H);
    int rem = idx % (H * H);
    int c = rem / H, k = rem % H;
    Wt123[idx] = f2bf(Wr[(size_t)l * H * H + k * H + c]);
}

// ---------------- layer-0 prescale: hs[n][c] = bf16(h[n][c] * dinv_src[n]) ----------------
// 1024-thread blocks: 4x fewer blocks (3125) -- launch-slot probe.
__global__ void k_prescale(const float* __restrict__ h, const float* __restrict__ dinv_s,
                           bf16_t* __restrict__ hs) {
    int idx = xcd_swz(blockIdx.x, 3125) * 1024 + threadIdx.x;   // over N * DIN/4
    if (idx >= N_NODES * (DIN / 4)) return;
    int n = idx >> 5;                                  // DIN/4 = 32
    float w = dinv_s[n];
    float4 v = reinterpret_cast<const float4*>(h)[idx];
    ushort4 o;
    o.x = f2bf(v.x * w); o.y = f2bf(v.y * w);
    o.z = f2bf(v.z * w); o.w = f2bf(v.w * w);
    reinterpret_cast<ushort4*>(hs)[idx] = o;
}

// ---------------- aggregation: one wave per node, CSR by dst ----------------
// 1024-thread blocks (16 nodes/block): 6250 blocks vs 25000 -- launch-slot probe.
template <int NC, bool PS>
__global__ void k_agg(const bf16_t* __restrict__ hx, const float* __restrict__ dinv_s,
                      const float* __restrict__ dinv_d, const int* __restrict__ row_start,
                      const int* __restrict__ csr_src, bf16_t* __restrict__ m) {
    constexpr int VEC = NC / 64;     // ushorts per lane (2 or 4)
    int gid  = xcd_swz(blockIdx.x, 6250) * 1024 + threadIdx.x;
    int v    = gid >> 6;
    int lane = gid & 63;
    if (v >= N_NODES) return;
    float acc[VEC] = {};
    int s0 = row_start[v], s1 = row_start[v + 1];

    auto body = [&](int ei) {
        int si = csr_src[ei];
        float wv = 1.f;
        if constexpr (!PS) wv = dinv_s[si];
        if constexpr (VEC == 4) {
            ushort4 r = *reinterpret_cast<const ushort4*>(hx + (size_t)si * NC + lane * 4);
            acc[0] += bf2f(r.x) * wv; acc[1] += bf2f(r.y) * wv;
            acc[2] += bf2f(r.z) * wv; acc[3] += bf2f(r.w) * wv;
        } else {
            ushort2 r = *reinterpret_cast<const ushort2*>(hx + (size_t)si * NC + lane * 2);
            acc[0] += bf2f(r.x) * wv; acc[1] += bf2f(r.y) * wv;
        }
    };

    int e = s0;
    for (; e + 3 < s1; e += 4) { body(e); body(e + 1); body(e + 2); body(e + 3); }
    for (; e < s1; ++e) body(e);

    float wd = dinv_d[v];
    if constexpr (VEC == 4) {
        ushort4 o;
        o.x = f2bf(acc[0] * wd); o.y = f2bf(acc[1] * wd);
        o.z = f2bf(acc[2] * wd); o.w = f2bf(acc[3] * wd);
        *reinterpret_cast<ushort4*>(m + (size_t)v * NC + lane * 4) = o;
    } else {
        ushort2 o; o.x = f2bf(acc[0] * wd); o.y = f2bf(acc[1] * wd);
        *reinterpret_cast<ushort2*>(m + (size_t)v * NC + lane * 2) = o;
    }
}

// ---------------- MFMA GEMM v15 (anchor, 48.5us): reg-staged A + ball prefetch ----------------
template <int K>
__global__ __launch_bounds__(256, 2) void k_gemm_mfma(const bf16_t* __restrict__ A,
                                                      const bf16_t* __restrict__ Wt,
                                                      const float* __restrict__ bias,
                                                      const unsigned int* __restrict__ relpk,
                                                      bf16_t* __restrict__ C,
                                                      float2* __restrict__ part) {
    __shared__ bf16_t lds_raw[64 * (H + 8)];            // 33792 B
    constexpr int LKA = K + 8;                          // padded A-tile row (shorts)
    bf16_t (*aT)[LKA] = reinterpret_cast<bf16_t (*)[LKA]>(lds_raw);
    bf16_t (*cT)[H + 8] = reinterpret_cast<bf16_t (*)[H + 8]>(lds_raw);
    constexpr int KS = K / 32;                          // 4 or 8 k-steps

    const int tid  = threadIdx.x;
    const int wave = tid >> 6;
    const int lane = tid & 63;
    const int pb   = xcd_swz(blockIdx.x, NBLK);         // swizzled tile id
    const int row0 = pb * 64;
    const int col0 = wave * 64;
    const int lr = lane & 15;    // fragment row (A) / col (B)
    const int lg = lane >> 4;    // k-group: k = 8*lg .. 8*lg+7

    // ---- B panel prefetch: all KS*4 independent loads issued up front ----
    const bf16_t* Bb = Wt + (size_t)(col0 + lr) * K + lg * 8;
    bf16x8 ball[KS][4];
    #pragma unroll
    for (int ks = 0; ks < KS; ++ks)
        #pragma unroll
        for (int nt = 0; nt < 4; ++nt)
            ball[ks][nt] = *reinterpret_cast<const bf16x8*>(Bb + (size_t)nt * 16 * K + ks * 32);

    // ---- stage A tile (64 rows x K, contiguous in global) into padded LDS ----
    {
        const bf16_t* Ag = A + (size_t)row0 * K;
        constexpr int CHUNKS = 64 * K / 8;              // 16B chunks in tile
        #pragma unroll
        for (int it = 0; it < CHUNKS / 256; ++it) {
            int ci  = it * 256 + tid;
            int row = (ci * 8) / K;
            int col = (ci * 8) % K;
            uint4 v = *reinterpret_cast<const uint4*>(Ag + ci * 8);
            *reinterpret_cast<uint4*>(&aT[row][col]) = v;
        }
    }
    __syncthreads();   // drains vmcnt: ball[] guaranteed resident too

    f32x4 acc[4][4] = {};        // [mtile][ntile], each 16x16

    #pragma unroll
    for (int ks = 0; ks < KS; ++ks) {
        bf16x8 a[4];
        #pragma unroll
        for (int mt = 0; mt < 4; ++mt)
            a[mt] = *reinterpret_cast<const bf16x8*>(&aT[mt * 16 + lr][ks * 32 + lg * 8]);
        #pragma unroll
        for (int mt = 0; mt < 4; ++mt)
            #pragma unroll
            for (int nt = 0; nt < 4; ++nt)
                acc[mt][nt] = __builtin_amdgcn_mfma_f32_16x16x32_bf16(a[mt], ball[ks][nt], acc[mt][nt], 0, 0, 0);
    }

    // ---- biases (used by both stats and C staging) ----
    float bsn[4];
    #pragma unroll
    for (int nt = 0; nt < 4; ++nt) bsn[nt] = bias[col0 + nt * 16 + lr];

    // ---- stats from accumulators: branch-free masked accumulate ----
    {
        unsigned int relw[4];
        #pragma unroll
        for (int mt = 0; mt < 4; ++mt)
            relw[mt] = relpk[pb * 16 + mt * 4 + lg];

        float sA[3][4] = {}, qA[3][4] = {};
        #pragma unroll
        for (int mt = 0; mt < 4; ++mt) {
            #pragma unroll
            for (int j = 0; j < 4; ++j) {
                int rv = (relw[mt] >> (8 * j)) & 0xff;
                #pragma unroll
                for (int nt = 0; nt < 4; ++nt) {
                    float v  = acc[mt][nt][j] + bsn[nt];
                    float v0 = (rv == 0) ? v : 0.f;
                    float v1 = (rv == 1) ? v : 0.f;
                    float v2 = (rv == 2) ? v : 0.f;
                    sA[0][nt] += v0; qA[0][nt] += v0 * v0;
                    sA[1][nt] += v1; qA[1][nt] += v1 * v1;
                    sA[2][nt] += v2; qA[2][nt] += v2 * v2;
                }
            }
        }
        // reduce across the 4 k-group lanes (lane ^16, ^32)
        #pragma unroll
        for (int rel = 0; rel < 3; ++rel) {
            #pragma unroll
            for (int nt = 0; nt < 4; ++nt) {
                float sv = sA[rel][nt], qv = qA[rel][nt];
                sv += __shfl_xor(sv, 16); qv += __shfl_xor(qv, 16);
                sv += __shfl_xor(sv, 32); qv += __shfl_xor(qv, 32);
                sA[rel][nt] = sv; qA[rel][nt] = qv;
            }
        }
        if (lg == 0) {
            constexpr size_t PLANE = (size_t)NBLK * H;
            #pragma unroll
            for (int rel = 0; rel < 3; ++rel)
                #pragma unroll
                for (int nt = 0; nt < 4; ++nt)
                    part[(size_t)rel * PLANE + (size_t)pb * H + col0 + nt * 16 + lr]
                        = make_float2(sA[rel][nt], qA[rel][nt]);
        }
    }

    __syncthreads();   // A tile fully consumed; reuse LDS for C staging

    // stage into LDS (C/D layout: col = lane&15, row = (lane>>4)*4 + reg)
    #pragma unroll
    for (int nt = 0; nt < 4; ++nt) {
        int c = col0 + nt * 16 + lr;
        #pragma unroll
        for (int mt = 0; mt < 4; ++mt) {
            #pragma unroll
            for (int j = 0; j < 4; ++j)
                cT[mt * 16 + lg * 4 + j][c] = f2bf(acc[mt][nt][j] + bsn[nt]);
        }
    }
    __syncthreads();

    // coalesced write: 64 rows x 256 cols x 2B; 16B per thread per iter
    #pragma unroll
    for (int it = 0; it < 8; ++it) {
        int i = it * 256 + tid;
        int r = i >> 5;          // 32 x 16B segments per 512B row
        int s = i & 31;
        *reinterpret_cast<uint4*>(C + (size_t)(row0 + r) * H + s * 8) =
            *reinterpret_cast<const uint4*>(&cT[r][s * 8]);
    }
}

// ---------------- fold partials -> per-graph scale/shift (fused k_scaleshift) ----------------
__global__ void k_stats_red(const float2* __restrict__ part, const int* __restrict__ bid,
                            const int* __restrict__ gstart, const float* __restrict__ countsf,
                            const float* __restrict__ gamma, const float* __restrict__ beta,
                            const float* __restrict__ msc,
                            float* __restrict__ scale, float* __restrict__ shift) {
    constexpr size_t PLANE = (size_t)NBLK * H;
    int b = blockIdx.x;
    int c = threadIdx.x;
    int n0 = gstart[b], n1 = gstart[b + 1];
    float s = 0.f, q = 0.f;
    if (n1 > n0) {
        int blo = n0 >> 6, bhi = (n1 - 1) >> 6;
        for (int blk = blo; blk <= bhi; ++blk) {
            int rel = b - bid[blk << 6];
            if (rel >= 0 && rel < 3) {
                float2 v = part[(size_t)rel * PLANE + (size_t)blk * H + c];
                s += v.x; q += v.y;
            }
        }
    }
    float rc   = 1.0f / countsf[b];
    float mean = s * rc, ex2 = q * rc;
    float mm   = mean * msc[c];
    float var  = ex2 - 2.f * mean * mm + mm * mm;
    float a    = gamma[c] * rsqrtf(var + EPSV);
    scale[b * H + c] = a;
    shift[b * H + c] = beta[c] - a * mm;
}

// ---------------- fused normalize + relu (+ residual): pure FMA stream ----------------
// 1024-thread blocks: 6250 blocks vs 25000 -- launch-slot probe.
template <bool RES>
__global__ void k_norm(const bf16_t* __restrict__ y, const bf16_t* __restrict__ resid,
                       const int* __restrict__ bid, const float* __restrict__ scale,
                       const float* __restrict__ shift, bf16_t* __restrict__ outp) {
    int idx = xcd_swz(blockIdx.x, 6250) * 1024 + threadIdx.x;  // over N*H/4
    if (idx >= N_NODES * (H / 4)) return;
    int n  = idx >> 6;      // 64 x ushort4 per row
    int f4 = idx & 63;
    int b  = bid[n];
    float4 sc = reinterpret_cast<const float4*>(scale)[b * 64 + f4];
    float4 sh = reinterpret_cast<const float4*>(shift)[b * 64 + f4];
    ushort4 yv = reinterpret_cast<const ushort4*>(y)[idx];
    float o0 = fmaxf(bf2f(yv.x) * sc.x + sh.x, 0.f);
    float o1 = fmaxf(bf2f(yv.y) * sc.y + sh.y, 0.f);
    float o2 = fmaxf(bf2f(yv.z) * sc.z + sh.z, 0.f);
    float o3 = fmaxf(bf2f(yv.w) * sc.w + sh.w, 0.f);
    if constexpr (RES) {
        ushort4 r = reinterpret_cast<const ushort4*>(resid)[idx];
        o0 += bf2f(r.x); o1 += bf2f(r.y); o2 += bf2f(r.z); o3 += bf2f(r.w);
    }
    ushort4 o;
    o.x = f2bf(o0); o.y = f2bf(o1); o.z = f2bf(o2); o.w = f2bf(o3);
    reinterpret_cast<ushort4*>(outp)[idx] = o;
}

// ---------------- pooling: per-slice partials (no atomics, no memset) ----------------
__global__ void k_pool(const bf16_t* __restrict__ hf, const int* __restrict__ gstart,
                       float* __restrict__ pp) {
    int b = blockIdx.x, sl = blockIdx.y, f = threadIdx.x;
    int n0 = gstart[b], n1 = gstart[b + 1];
    int cnt = n1 - n0;
    int lo = n0 + (int)((long long)cnt * sl / PSLICES);
    int hi = n0 + (int)((long long)cnt * (sl + 1) / PSLICES);
    float s = 0.f;
    for (int n = lo; n < hi; ++n) s += bf2f(hf[(size_t)n * H + f]);
    pp[((size_t)b * PSLICES + sl) * H + f] = s;
}

__global__ void k_pred(const float* __restrict__ pp, const float* __restrict__ Wp,
                       const float* __restrict__ bp, float* __restrict__ outp) {
    __shared__ float row[H];
    int b = blockIdx.x, f = threadIdx.x;
    float s = 0.f;
    for (int sl = 0; sl < PSLICES; ++sl)
        s += pp[((size_t)b * PSLICES + sl) * H + f];
    row[f] = s;
    __syncthreads();
    if (f < OUT_DIM) {
        float acc = bp[f];
        for (int k = 0; k < H; ++k) acc += row[k] * Wp[k * OUT_DIM + f];
        outp[b * OUT_DIM + f] = acc;
    }
}

extern "C" void kernel_launch(void* const* d_in, const int* in_sizes, int n_in,
                              void* d_out, int out_size, void* d_ws, size_t ws_size,
                              hipStream_t stream) {
    const float* h_in  = (const float*)d_in[0];
    const int*   src   = (const int*)d_in[1];
    const int*   dst   = (const int*)d_in[2];
    const int*   bid   = (const int*)d_in[3];
    const float* Wf    = (const float*)d_in[4];
    const float* bfv   = (const float*)d_in[5];
    const float* Wr    = (const float*)d_in[6];
    const float* br    = (const float*)d_in[7];
    const float* gamma = (const float*)d_in[8];
    const float* beta  = (const float*)d_in[9];
    const float* ms    = (const float*)d_in[10];
    const float* Wp    = (const float*)d_in[11];
    const float* bp    = (const float*)d_in[12];
    float* outp = (float*)d_out;

    char* w = (char*)d_ws;
    size_t off = 0;
    auto alloc = [&](size_t bytes) -> void* {
        void* p = w + off;
        off = (off + bytes + 255) & ~(size_t)255;
        return p;
    };
    bf16_t* bufA = (bf16_t*)alloc((size_t)N_PAD * H * 2);
    bf16_t* bufB = (bf16_t*)alloc((size_t)N_PAD * H * 2);
    bf16_t* bufC = (bf16_t*)alloc((size_t)N_PAD * H * 2);
    bf16_t* Wt0  = (bf16_t*)alloc((size_t)H * DIN * 2);
    bf16_t* Wt123= (bf16_t*)alloc((size_t)3 * H * H * 2);
    int* deg       = (int*)alloc((size_t)2 * N_NODES * 4);  // [out | in]
    float* dinv_src = (float*)alloc(N_NODES * 4);
    float* dinv_dst = (float*)alloc(N_NODES * 4);
    int* incl_tmp  = (int*)alloc(N_NODES * 4);
    int* bsums     = (int*)alloc(512 * 4);
    int* boffs     = (int*)alloc(512 * 4);
    int* row_start = (int*)alloc((N_NODES + 1) * 4);
    int* cursor    = (int*)alloc(N_NODES * 4);
    int* csr_src   = (int*)alloc(N_EDGES * 4);
    int* gstart    = (int*)alloc((NB + 1) * 4);
    float* countsf = (float*)alloc(NB * 4);
    float* gscale  = (float*)alloc((size_t)NB * H * 4);
    float* gshift  = (float*)alloc((size_t)NB * H * 4);
    float2* part   = (float2*)alloc((size_t)3 * NBLK * H * 8);   // 9.6 MB
    unsigned int* relpk = (unsigned int*)alloc((size_t)NBLK * 16 * 4);
    float* pp      = (float*)alloc((size_t)NB * PSLICES * H * 4);   // 4 MB

    if (off > ws_size) return;   // clean failure instead of OOB

    // hs (prescaled layer-0 input, [N][128] bf16) lives in bufB: it is fully
    // consumed by k_agg before k_gemm_mfma overwrites bufB.
    bf16_t* hs = bufB;

    const int nscan = (N_NODES + SCAN_B - 1) / SCAN_B;

    hipMemsetAsync(deg, 0, (size_t)2 * N_NODES * 4, stream);

    k_edge_deg<<<(N_EDGES + 255) / 256, 256, 0, stream>>>(src, dst, deg);
    k_gstart_relpk<<<(NBLK * 16 + 255) / 256, 256, 0, stream>>>(bid, gstart, countsf, relpk);
    k_scan1<<<nscan, SCAN_B, 0, stream>>>(deg + N_NODES, incl_tmp, bsums);
    k_scan2<<<1, 512, 0, stream>>>(bsums, boffs, nscan);
    k_scan3<<<(N_NODES + 255) / 256, 256, 0, stream>>>(deg, incl_tmp, boffs, row_start, cursor,
                                                       dinv_src, dinv_dst);
    k_scatter<<<(N_EDGES + 255) / 256, 256, 0, stream>>>(src, dst, cursor, csr_src);
    k_wt<<<(H * DIN + 3 * H * H + 255) / 256, 256, 0, stream>>>(Wf, Wr, Wt0, Wt123);

    const int aggGrid  = 6250;   // 1024-thread blocks, 16 nodes each
    const int normGrid = 6250;   // 1024-thread blocks

    // ---- layer 0: prescale (bf16) + bf16 aggregation ----
    k_prescale<<<3125, 1024, 0, stream>>>(h_in, dinv_src, hs);
    k_agg<DIN, true><<<aggGrid, 1024, 0, stream>>>(hs, nullptr, dinv_dst, row_start, csr_src, bufA);
    k_gemm_mfma<DIN><<<NBLK, 256, 0, stream>>>(bufA, Wt0, bfv, relpk, bufB, part);
    k_stats_red<<<NB, H, 0, stream>>>(part, bid, gstart, countsf, gamma, beta, ms,
                                      gscale, gshift);
    k_norm<false><<<normGrid, 1024, 0, stream>>>(bufB, nullptr, bid, gscale, gshift, bufC);

    // ---- layers 1..3 ----
    bf16_t* hx = bufC;
    bf16_t* f1 = bufA;
    bf16_t* f2 = bufB;
    for (int i = 1; i < 4; ++i) {
        k_agg<H, false><<<aggGrid, 1024, 0, stream>>>(hx, dinv_src, dinv_dst, row_start, csr_src, f1);
        k_gemm_mfma<H><<<NBLK, 256, 0, stream>>>(f1, Wt123 + (size_t)(i - 1) * H * H,
                                                 br + (i - 1) * H, relpk, f2, part);
        k_stats_red<<<NB, H, 0, stream>>>(part, bid, gstart, countsf, gamma + i * H,
                                          beta + i * H, ms + i * H, gscale, gshift);
        k_norm<true><<<normGrid, 1024, 0, stream>>>(f2, hx, bid, gscale, gshift, f1);
        bf16_t* nh = f1; f1 = hx; hx = nh;
    }

    k_pool<<<dim3(NB, PSLICES), H, 0, stream>>>(hx, gstart, pp);
    k_pred<<<NB, H, 0, stream>>>(pp, Wp, bp, outp);
}

// Round 17
// 560.232 us; speedup vs baseline: 1.0462x; 1.0462x over previous
//
#include <hip/hip_runtime.h>

#define N_NODES 100000
#define N_PAD   100096   // multiple of 64 for GEMM block tiles
#define N_EDGES 320000
#define NB      128
#define DIN     128
#define H       256
#define OUT_DIM 10
#define EPSV    1e-6f
#define SCAN_B  256
#define PSLICES 32
#define NBLK    (N_PAD / 64)   // 1564 GEMM row-tiles (BM=64)
#define NXCD    8

typedef unsigned short bf16_t;
typedef __attribute__((ext_vector_type(8))) short bf16x8;
typedef __attribute__((ext_vector_type(4))) float f32x4;

__device__ __forceinline__ float bf2f(bf16_t u) {
    union { unsigned int i; float f; } x;
    x.i = ((unsigned int)u) << 16;
    return x.f;
}
__device__ __forceinline__ bf16_t f2bf(float f) {
    union { float f; unsigned int i; } x;
    x.f = f;
    unsigned int r = x.i + 0x7fffu + ((x.i >> 16) & 1u);   // round-to-nearest-even
    return (bf16_t)(r >> 16);
}

// Bijective XCD-chunked blockIdx swizzle (m204 variant; works for nwg%8 != 0).
__device__ __forceinline__ int xcd_swz(int bid, int nwg) {
    int q = nwg / NXCD, r = nwg % NXCD;
    int x = bid % NXCD, j = bid / NXCD;
    int base = (x < r) ? x * (q + 1) : r * (q + 1) + (x - r) * q;
    return base + j;
}

// ---------------- degree (deg_out = deg[0:N], deg_in = deg[N:2N]) ----------------
__global__ void k_edge_deg(const int* __restrict__ src, const int* __restrict__ dst,
                           int* deg) {
    int e = blockIdx.x * blockDim.x + threadIdx.x;
    if (e < N_EDGES) {
        atomicAdd(&deg[src[e]], 1);
        atomicAdd(&deg[N_NODES + dst[e]], 1);
    }
}

// ---------------- fused: graph offsets (block 0) + packed rel table (all blocks) ----------------
__global__ void k_gstart_relpk(const int* __restrict__ bid, int* __restrict__ gstart,
                               float* __restrict__ countsf, unsigned int* __restrict__ relpk) {
    if (blockIdx.x == 0) {
        int b = threadIdx.x;
        if (b <= NB) {
            int lo = 0, hi = N_NODES;
            while (lo < hi) {
                int mid = (lo + hi) >> 1;
                if (bid[mid] < b) lo = mid + 1; else hi = mid;
            }
            gstart[b] = lo;
        }
        __syncthreads();
        if (b < NB) countsf[b] = (float)max(gstart[b + 1] - gstart[b], 1);
    }
    int idx = blockIdx.x * blockDim.x + threadIdx.x;   // over NBLK*16
    if (idx >= NBLK * 16) return;
    int t = idx >> 4, w = idx & 15;
    int row0 = t * 64;
    int g0 = bid[(row0 < N_NODES) ? row0 : (N_NODES - 1)];
    unsigned int pk = 0;
    for (int j = 0; j < 4; ++j) {
        int r = row0 + w * 4 + j;
        unsigned int rel = 255u;
        if (r < N_NODES) {
            int d = bid[r] - g0;
            rel = (d >= 0 && d < 255) ? (unsigned int)d : 255u;
        }
        pk |= rel << (8 * j);
    }
    relpk[idx] = pk;
}

// ---------------- hierarchical scan for CSR row_start ----------------
__global__ void k_scan1(const int* __restrict__ deg_in, int* incl, int* bsums) {
    __shared__ int s[SCAN_B];
    int i = blockIdx.x * SCAN_B + threadIdx.x;
    int v = (i < N_NODES) ? deg_in[i] : 0;
    s[threadIdx.x] = v;
    __syncthreads();
    for (int d = 1; d < SCAN_B; d <<= 1) {
        int t = (threadIdx.x >= d) ? s[threadIdx.x - d] : 0;
        __syncthreads();
        s[threadIdx.x] += t;
        __syncthreads();
    }
    if (i < N_NODES) incl[i] = s[threadIdx.x];
    if (threadIdx.x == SCAN_B - 1) bsums[blockIdx.x] = s[threadIdx.x];
}

__global__ void k_scan2(const int* __restrict__ bsums, int* boffs, int nb) {
    __shared__ int s[512];
    int t = threadIdx.x;
    int v = (t < nb) ? bsums[t] : 0;
    s[t] = v;
    __syncthreads();
    for (int d = 1; d < 512; d <<= 1) {
        int x = (t >= d) ? s[t - d] : 0;
        __syncthreads();
        s[t] += x;
        __syncthreads();
    }
    if (t < nb) boffs[t] = s[t] - v;   // exclusive
}

// scan3 + dinv fused (same grid, independent outputs)
__global__ void k_scan3(const int* __restrict__ deg, const int* __restrict__ incl,
                        const int* __restrict__ boffs, int* row_start, int* cursor,
                        float* dinv_src, float* dinv_dst) {
    int i = blockIdx.x * blockDim.x + threadIdx.x;
    if (i < N_NODES) {
        int ex = incl[i] - deg[N_NODES + i] + boffs[i / SCAN_B];
        row_start[i] = ex;
        cursor[i]    = ex;
        dinv_src[i] = rsqrtf((float)max(deg[i], 1));
        dinv_dst[i] = rsqrtf((float)max(deg[N_NODES + i], 1));
    }
    if (i == 0) row_start[N_NODES] = N_EDGES;
}

__global__ void k_scatter(const int* __restrict__ src, const int* __restrict__ dst,
                          int* cursor, int* csr_src) {
    int e = blockIdx.x * blockDim.x + threadIdx.x;
    if (e < N_EDGES) {
        int slot = atomicAdd(&cursor[dst[e]], 1);
        csr_src[slot] = src[e];
    }
}

// ---------------- weight convert + transpose (both tensors, one kernel) ----------------
__global__ void k_wt(const float* __restrict__ Wf, const float* __restrict__ Wr,
                     bf16_t* __restrict__ Wt0, bf16_t* __restrict__ Wt123) {
    int idx = blockIdx.x * 256 + threadIdx.x;
    if (idx < H * DIN) {                        // Wt0[c][k] = bf16(Wf[k][c])
        int c = idx / DIN, k = idx % DIN;
        Wt0[idx] = f2bf(Wf[k * H + c]);
        return;
    }
    idx -= H * DIN;
    if (idx >= 3 * H * H) return;               // Wt123[l][c][k] = bf16(Wr[l][k][c])
    int l = idx / (H * H);
    int rem = idx % (H * H);
    int c = rem / H, k = rem % H;
    Wt123[idx] = f2bf(Wr[(size_t)l * H * H + k * H + c]);
}

// ---------------- layer-0 prescale: hs[n][c] = bf16(h[n][c] * dinv_src[n]) ----------------
__global__ void k_prescale(const float* __restrict__ h, const float* __restrict__ dinv_s,
                           bf16_t* __restrict__ hs) {
    int idx = xcd_swz(blockIdx.x, 12500) * 256 + threadIdx.x;   // over N * DIN/4
    if (idx >= N_NODES * (DIN / 4)) return;
    int n = idx >> 5;                                  // DIN/4 = 32
    float w = dinv_s[n];
    float4 v = reinterpret_cast<const float4*>(h)[idx];
    ushort4 o;
    o.x = f2bf(v.x * w); o.y = f2bf(v.y * w);
    o.z = f2bf(v.z * w); o.w = f2bf(v.w * w);
    reinterpret_cast<ushort4*>(hs)[idx] = o;
}

// ---------------- aggregation: one wave per node, CSR by dst ----------------
template <int NC, bool PS>
__global__ void k_agg(const bf16_t* __restrict__ hx, const float* __restrict__ dinv_s,
                      const float* __restrict__ dinv_d, const int* __restrict__ row_start,
                      const int* __restrict__ csr_src, bf16_t* __restrict__ m) {
    constexpr int VEC = NC / 64;     // ushorts per lane (2 or 4)
    int gid  = xcd_swz(blockIdx.x, 25000) * blockDim.x + threadIdx.x;
    int v    = gid >> 6;
    int lane = gid & 63;
    if (v >= N_NODES) return;
    float acc[VEC] = {};
    int s0 = row_start[v], s1 = row_start[v + 1];

    auto body = [&](int ei) {
        int si = csr_src[ei];
        float wv = 1.f;
        if constexpr (!PS) wv = dinv_s[si];
        if constexpr (VEC == 4) {
            ushort4 r = *reinterpret_cast<const ushort4*>(hx + (size_t)si * NC + lane * 4);
            acc[0] += bf2f(r.x) * wv; acc[1] += bf2f(r.y) * wv;
            acc[2] += bf2f(r.z) * wv; acc[3] += bf2f(r.w) * wv;
        } else {
            ushort2 r = *reinterpret_cast<const ushort2*>(hx + (size_t)si * NC + lane * 2);
            acc[0] += bf2f(r.x) * wv; acc[1] += bf2f(r.y) * wv;
        }
    };

    int e = s0;
    for (; e + 3 < s1; e += 4) { body(e); body(e + 1); body(e + 2); body(e + 3); }
    for (; e < s1; ++e) body(e);

    float wd = dinv_d[v];
    if constexpr (VEC == 4) {
        ushort4 o;
        o.x = f2bf(acc[0] * wd); o.y = f2bf(acc[1] * wd);
        o.z = f2bf(acc[2] * wd); o.w = f2bf(acc[3] * wd);
        *reinterpret_cast<ushort4*>(m + (size_t)v * NC + lane * 4) = o;
    } else {
        ushort2 o; o.x = f2bf(acc[0] * wd); o.y = f2bf(acc[1] * wd);
        *reinterpret_cast<ushort2*>(m + (size_t)v * NC + lane * 2) = o;
    }
}

// ---------------- MFMA GEMM v15 (anchor, 48.5us): reg-staged A + ball prefetch ----------------
template <int K>
__global__ __launch_bounds__(256, 2) void k_gemm_mfma(const bf16_t* __restrict__ A,
                                                      const bf16_t* __restrict__ Wt,
                                                      const float* __restrict__ bias,
                                                      const unsigned int* __restrict__ relpk,
                                                      bf16_t* __restrict__ C,
                                                      float2* __restrict__ part) {
    __shared__ bf16_t lds_raw[64 * (H + 8)];            // 33792 B
    constexpr int LKA = K + 8;                          // padded A-tile row (shorts)
    bf16_t (*aT)[LKA] = reinterpret_cast<bf16_t (*)[LKA]>(lds_raw);
    bf16_t (*cT)[H + 8] = reinterpret_cast<bf16_t (*)[H + 8]>(lds_raw);
    constexpr int KS = K / 32;                          // 4 or 8 k-steps

    const int tid  = threadIdx.x;
    const int wave = tid >> 6;
    const int lane = tid & 63;
    const int pb   = xcd_swz(blockIdx.x, NBLK);         // swizzled tile id
    const int row0 = pb * 64;
    const int col0 = wave * 64;
    const int lr = lane & 15;    // fragment row (A) / col (B)
    const int lg = lane >> 4;    // k-group: k = 8*lg .. 8*lg+7

    // ---- B panel prefetch: all KS*4 independent loads issued up front ----
    const bf16_t* Bb = Wt + (size_t)(col0 + lr) * K + lg * 8;
    bf16x8 ball[KS][4];
    #pragma unroll
    for (int ks = 0; ks < KS; ++ks)
        #pragma unroll
        for (int nt = 0; nt < 4; ++nt)
            ball[ks][nt] = *reinterpret_cast<const bf16x8*>(Bb + (size_t)nt * 16 * K + ks * 32);

    // ---- stage A tile (64 rows x K, contiguous in global) into padded LDS ----
    {
        const bf16_t* Ag = A + (size_t)row0 * K;
        constexpr int CHUNKS = 64 * K / 8;              // 16B chunks in tile
        #pragma unroll
        for (int it = 0; it < CHUNKS / 256; ++it) {
            int ci  = it * 256 + tid;
            int row = (ci * 8) / K;
            int col = (ci * 8) % K;
            uint4 v = *reinterpret_cast<const uint4*>(Ag + ci * 8);
            *reinterpret_cast<uint4*>(&aT[row][col]) = v;
        }
    }
    __syncthreads();   // drains vmcnt: ball[] guaranteed resident too

    f32x4 acc[4][4] = {};        // [mtile][ntile], each 16x16

    #pragma unroll
    for (int ks = 0; ks < KS; ++ks) {
        bf16x8 a[4];
        #pragma unroll
        for (int mt = 0; mt < 4; ++mt)
            a[mt] = *reinterpret_cast<const bf16x8*>(&aT[mt * 16 + lr][ks * 32 + lg * 8]);
        #pragma unroll
        for (int mt = 0; mt < 4; ++mt)
            #pragma unroll
            for (int nt = 0; nt < 4; ++nt)
                acc[mt][nt] = __builtin_amdgcn_mfma_f32_16x16x32_bf16(a[mt], ball[ks][nt], acc[mt][nt], 0, 0, 0);
    }

    // ---- biases (used by both stats and C staging) ----
    float bsn[4];
    #pragma unroll
    for (int nt = 0; nt < 4; ++nt) bsn[nt] = bias[col0 + nt * 16 + lr];

    // ---- stats from accumulators: branch-free masked accumulate ----
    {
        unsigned int relw[4];
        #pragma unroll
        for (int mt = 0; mt < 4; ++mt)
            relw[mt] = relpk[pb * 16 + mt * 4 + lg];

        float sA[3][4] = {}, qA[3][4] = {};
        #pragma unroll
        for (int mt = 0; mt < 4; ++mt) {
            #pragma unroll
            for (int j = 0; j < 4; ++j) {
                int rv = (relw[mt] >> (8 * j)) & 0xff;
                #pragma unroll
                for (int nt = 0; nt < 4; ++nt) {
                    float v  = acc[mt][nt][j] + bsn[nt];
                    float v0 = (rv == 0) ? v : 0.f;
                    float v1 = (rv == 1) ? v : 0.f;
                    float v2 = (rv == 2) ? v : 0.f;
                    sA[0][nt] += v0; qA[0][nt] += v0 * v0;
                    sA[1][nt] += v1; qA[1][nt] += v1 * v1;
                    sA[2][nt] += v2; qA[2][nt] += v2 * v2;
                }
            }
        }
        // reduce across the 4 k-group lanes (lane ^16, ^32)
        #pragma unroll
        for (int rel = 0; rel < 3; ++rel) {
            #pragma unroll
            for (int nt = 0; nt < 4; ++nt) {
                float sv = sA[rel][nt], qv = qA[rel][nt];
                sv += __shfl_xor(sv, 16); qv += __shfl_xor(qv, 16);
                sv += __shfl_xor(sv, 32); qv += __shfl_xor(qv, 32);
                sA[rel][nt] = sv; qA[rel][nt] = qv;
            }
        }
        if (lg == 0) {
            constexpr size_t PLANE = (size_t)NBLK * H;
            #pragma unroll
            for (int rel = 0; rel < 3; ++rel)
                #pragma unroll
                for (int nt = 0; nt < 4; ++nt)
                    part[(size_t)rel * PLANE + (size_t)pb * H + col0 + nt * 16 + lr]
                        = make_float2(sA[rel][nt], qA[rel][nt]);
        }
    }

    __syncthreads();   // A tile fully consumed; reuse LDS for C staging

    // stage into LDS (C/D layout: col = lane&15, row = (lane>>4)*4 + reg)
    #pragma unroll
    for (int nt = 0; nt < 4; ++nt) {
        int c = col0 + nt * 16 + lr;
        #pragma unroll
        for (int mt = 0; mt < 4; ++mt) {
            #pragma unroll
            for (int j = 0; j < 4; ++j)
                cT[mt * 16 + lg * 4 + j][c] = f2bf(acc[mt][nt][j] + bsn[nt]);
        }
    }
    __syncthreads();

    // coalesced write: 64 rows x 256 cols x 2B; 16B per thread per iter
    #pragma unroll
    for (int it = 0; it < 8; ++it) {
        int i = it * 256 + tid;
        int r = i >> 5;          // 32 x 16B segments per 512B row
        int s = i & 31;
        *reinterpret_cast<uint4*>(C + (size_t)(row0 + r) * H + s * 8) =
            *reinterpret_cast<const uint4*>(&cT[r][s * 8]);
    }
}

// ---------------- fold partials -> per-graph scale/shift (fused k_scaleshift) ----------------
__global__ void k_stats_red(const float2* __restrict__ part, const int* __restrict__ bid,
                            const int* __restrict__ gstart, const float* __restrict__ countsf,
                            const float* __restrict__ gamma, const float* __restrict__ beta,
                            const float* __restrict__ msc,
                            float* __restrict__ scale, float* __restrict__ shift) {
    constexpr size_t PLANE = (size_t)NBLK * H;
    int b = blockIdx.x;
    int c = threadIdx.x;
    int n0 = gstart[b], n1 = gstart[b + 1];
    float s = 0.f, q = 0.f;
    if (n1 > n0) {
        int blo = n0 >> 6, bhi = (n1 - 1) >> 6;
        for (int blk = blo; blk <= bhi; ++blk) {
            int rel = b - bid[blk << 6];
            if (rel >= 0 && rel < 3) {
                float2 v = part[(size_t)rel * PLANE + (size_t)blk * H + c];
                s += v.x; q += v.y;
            }
        }
    }
    float rc   = 1.0f / countsf[b];
    float mean = s * rc, ex2 = q * rc;
    float mm   = mean * msc[c];
    float var  = ex2 - 2.f * mean * mm + mm * mm;
    float a    = gamma[c] * rsqrtf(var + EPSV);
    scale[b * H + c] = a;
    shift[b * H + c] = beta[c] - a * mm;
}

// ---------------- fused normalize + relu (+ residual): pure FMA stream ----------------
template <bool RES>
__global__ void k_norm(const bf16_t* __restrict__ y, const bf16_t* __restrict__ resid,
                       const int* __restrict__ bid, const float* __restrict__ scale,
                       const float* __restrict__ shift, bf16_t* __restrict__ outp) {
    int idx = xcd_swz(blockIdx.x, 25000) * 256 + threadIdx.x;  // over N*H/4
    if (idx >= N_NODES * (H / 4)) return;
    int n  = idx >> 6;      // 64 x ushort4 per row
    int f4 = idx & 63;
    int b  = bid[n];
    float4 sc = reinterpret_cast<const float4*>(scale)[b * 64 + f4];
    float4 sh = reinterpret_cast<const float4*>(shift)[b * 64 + f4];
    ushort4 yv = reinterpret_cast<const ushort4*>(y)[idx];
    float o0 = fmaxf(bf2f(yv.x) * sc.x + sh.x, 0.f);
    float o1 = fmaxf(bf2f(yv.y) * sc.y + sh.y, 0.f);
    float o2 = fmaxf(bf2f(yv.z) * sc.z + sh.z, 0.f);
    float o3 = fmaxf(bf2f(yv.w) * sc.w + sh.w, 0.f);
    if constexpr (RES) {
        ushort4 r = reinterpret_cast<const ushort4*>(resid)[idx];
        o0 += bf2f(r.x); o1 += bf2f(r.y); o2 += bf2f(r.z); o3 += bf2f(r.w);
    }
    ushort4 o;
    o.x = f2bf(o0); o.y = f2bf(o1); o.z = f2bf(o2); o.w = f2bf(o3);
    reinterpret_cast<ushort4*>(outp)[idx] = o;
}

// ---------------- pooling: per-slice partials (no atomics, no memset) ----------------
__global__ void k_pool(const bf16_t* __restrict__ hf, const int* __restrict__ gstart,
                       float* __restrict__ pp) {
    int b = blockIdx.x, sl = blockIdx.y, f = threadIdx.x;
    int n0 = gstart[b], n1 = gstart[b + 1];
    int cnt = n1 - n0;
    int lo = n0 + (int)((long long)cnt * sl / PSLICES);
    int hi = n0 + (int)((long long)cnt * (sl + 1) / PSLICES);
    float s = 0.f;
    for (int n = lo; n < hi; ++n) s += bf2f(hf[(size_t)n * H + f]);
    pp[((size_t)b * PSLICES + sl) * H + f] = s;
}

__global__ void k_pred(const float* __restrict__ pp, const float* __restrict__ Wp,
                       const float* __restrict__ bp, float* __restrict__ outp) {
    __shared__ float row[H];
    int b = blockIdx.x, f = threadIdx.x;
    float s = 0.f;
    for (int sl = 0; sl < PSLICES; ++sl)
        s += pp[((size_t)b * PSLICES + sl) * H + f];
    row[f] = s;
    __syncthreads();
    if (f < OUT_DIM) {
        float acc = bp[f];
        for (int k = 0; k < H; ++k) acc += row[k] * Wp[k * OUT_DIM + f];
        outp[b * OUT_DIM + f] = acc;
    }
}

extern "C" void kernel_launch(void* const* d_in, const int* in_sizes, int n_in,
                              void* d_out, int out_size, void* d_ws, size_t ws_size,
                              hipStream_t stream) {
    const float* h_in  = (const float*)d_in[0];
    const int*   src   = (const int*)d_in[1];
    const int*   dst   = (const int*)d_in[2];
    const int*   bid   = (const int*)d_in[3];
    const float* Wf    = (const float*)d_in[4];
    const float* bfv   = (const float*)d_in[5];
    const float* Wr    = (const float*)d_in[6];
    const float* br    = (const float*)d_in[7];
    const float* gamma = (const float*)d_in[8];
    const float* beta  = (const float*)d_in[9];
    const float* ms    = (const float*)d_in[10];
    const float* Wp    = (const float*)d_in[11];
    const float* bp    = (const float*)d_in[12];
    float* outp = (float*)d_out;

    char* w = (char*)d_ws;
    size_t off = 0;
    auto alloc = [&](size_t bytes) -> void* {
        void* p = w + off;
        off = (off + bytes + 255) & ~(size_t)255;
        return p;
    };
    bf16_t* bufA = (bf16_t*)alloc((size_t)N_PAD * H * 2);
    bf16_t* bufB = (bf16_t*)alloc((size_t)N_PAD * H * 2);
    bf16_t* bufC = (bf16_t*)alloc((size_t)N_PAD * H * 2);
    bf16_t* Wt0  = (bf16_t*)alloc((size_t)H * DIN * 2);
    bf16_t* Wt123= (bf16_t*)alloc((size_t)3 * H * H * 2);
    int* deg       = (int*)alloc((size_t)2 * N_NODES * 4);  // [out | in]
    float* dinv_src = (float*)alloc(N_NODES * 4);
    float* dinv_dst = (float*)alloc(N_NODES * 4);
    int* incl_tmp  = (int*)alloc(N_NODES * 4);
    int* bsums     = (int*)alloc(512 * 4);
    int* boffs     = (int*)alloc(512 * 4);
    int* row_start = (int*)alloc((N_NODES + 1) * 4);
    int* cursor    = (int*)alloc(N_NODES * 4);
    int* csr_src   = (int*)alloc(N_EDGES * 4);
    int* gstart    = (int*)alloc((NB + 1) * 4);
    float* countsf = (float*)alloc(NB * 4);
    float* gscale  = (float*)alloc((size_t)NB * H * 4);
    float* gshift  = (float*)alloc((size_t)NB * H * 4);
    float2* part   = (float2*)alloc((size_t)3 * NBLK * H * 8);   // 9.6 MB
    unsigned int* relpk = (unsigned int*)alloc((size_t)NBLK * 16 * 4);
    float* pp      = (float*)alloc((size_t)NB * PSLICES * H * 4);   // 4 MB

    if (off > ws_size) return;   // clean failure instead of OOB

    // hs (prescaled layer-0 input, [N][128] bf16) lives in bufB: it is fully
    // consumed by k_agg before k_gemm_mfma overwrites bufB.
    bf16_t* hs = bufB;

    const int nscan = (N_NODES + SCAN_B - 1) / SCAN_B;

    hipMemsetAsync(deg, 0, (size_t)2 * N_NODES * 4, stream);

    k_edge_deg<<<(N_EDGES + 255) / 256, 256, 0, stream>>>(src, dst, deg);
    k_gstart_relpk<<<(NBLK * 16 + 255) / 256, 256, 0, stream>>>(bid, gstart, countsf, relpk);
    k_scan1<<<nscan, SCAN_B, 0, stream>>>(deg + N_NODES, incl_tmp, bsums);
    k_scan2<<<1, 512, 0, stream>>>(bsums, boffs, nscan);
    k_scan3<<<(N_NODES + 255) / 256, 256, 0, stream>>>(deg, incl_tmp, boffs, row_start, cursor,
                                                       dinv_src, dinv_dst);
    k_scatter<<<(N_EDGES + 255) / 256, 256, 0, stream>>>(src, dst, cursor, csr_src);
    k_wt<<<(H * DIN + 3 * H * H + 255) / 256, 256, 0, stream>>>(Wf, Wr, Wt0, Wt123);

    const int aggGrid  = (N_NODES + 3) / 4;                  // 25000 exactly
    const int normGrid = (N_NODES * (H / 4) + 255) / 256;    // 25000 exactly

    // ---- layer 0: prescale (bf16) + bf16 aggregation ----
    k_prescale<<<(N_NODES * (DIN / 4) + 255) / 256, 256, 0, stream>>>(h_in, dinv_src, hs);
    k_agg<DIN, true><<<aggGrid, 256, 0, stream>>>(hs, nullptr, dinv_dst, row_start, csr_src, bufA);
    k_gemm_mfma<DIN><<<NBLK, 256, 0, stream>>>(bufA, Wt0, bfv, relpk, bufB, part);
    k_stats_red<<<NB, H, 0, stream>>>(part, bid, gstart, countsf, gamma, beta, ms,
                                      gscale, gshift);
    k_norm<false><<<normGrid, 256, 0, stream>>>(bufB, nullptr, bid, gscale, gshift, bufC);

    // ---- layers 1..3 ----
    bf16_t* hx = bufC;
    bf16_t* f1 = bufA;
    bf16_t* f2 = bufB;
    for (int i = 1; i < 4; ++i) {
        k_agg<H, false><<<aggGrid, 256, 0, stream>>>(hx, dinv_src, dinv_dst, row_start, csr_src, f1);
        k_gemm_mfma<H><<<NBLK, 256, 0, stream>>>(f1, Wt123 + (size_t)(i - 1) * H * H,
                                                 br + (i - 1) * H, relpk, f2, part);
        k_stats_red<<<NB, H, 0, stream>>>(part, bid, gstart, countsf, gamma + i * H,
                                          beta + i * H, ms + i * H, gscale, gshift);
        k_norm<true><<<normGrid, 256, 0, stream>>>(f2, hx, bid, gscale, gshift, f1);
        bf16_t* nh = f1; f1 = hx; hx = nh;
    }

    k_pool<<<dim3(NB, PSLICES), H, 0, stream>>>(hx, gstart, pp);
    k_pred<<<NB, H, 0, stream>>>(pp, Wp, bp, outp);
}